// Round 6
// baseline (256.990 us; speedup 1.0000x reference)
//
#include <hip/hip_runtime.h>
#include <math.h>

typedef unsigned short u16;
typedef unsigned int u32;
typedef __attribute__((ext_vector_type(8))) short short8;
typedef __attribute__((ext_vector_type(4))) float f32x4;

// ---------- helpers ----------
__device__ __forceinline__ u16 f2bf(float f) {
  union { float f; unsigned u; } x; x.f = f;
  unsigned r = x.u + 0x7FFFu + ((x.u >> 16) & 1u);   // RNE
  return (u16)(r >> 16);
}

__device__ __forceinline__ u32 asu(float f) {
  union { float f; u32 u; } x; x.f = f; return x.u;
}

// pack two floats -> two bf16 (round-half-up) in one u32: lo=a, hi=b
__device__ __forceinline__ u32 pack2bf(float a, float b) {
  return __builtin_amdgcn_perm(asu(b) + 0x8000u, asu(a) + 0x8000u, 0x07060302u);
}

__device__ __forceinline__ void gld_lds16(const void* g, void* l) {
  __builtin_amdgcn_global_load_lds(
      (const __attribute__((address_space(1))) unsigned int*)g,
      (__attribute__((address_space(3))) unsigned int*)l, 16, 0, 0);
}

// ---------- fused preprocessing: cast Xq/Xc + transpose all weights ----------
__global__ void pre_kernel(const float* __restrict__ q, const float* __restrict__ c,
                           const float* __restrict__ Wq, const float* __restrict__ Wkv,
                           const float* __restrict__ Wo,
                           u16* __restrict__ xq, u16* __restrict__ xc,
                           u16* __restrict__ WqT, u16* __restrict__ WkvT,
                           u16* __restrict__ WoT) {
  __shared__ float tile[32][33];
  int bx = blockIdx.x, t = threadIdx.x;
  if (bx < 8192) {
    int i = bx * 256 + t;
    const float* src = q; u16* dst = xq;
    if (i >= 1048576) { i -= 1048576; src = c; dst = xc; }
    float4 v = ((const float4*)src)[i];
    ((uint2*)dst)[i] = make_uint2(
        (unsigned)f2bf(v.x) | ((unsigned)f2bf(v.y) << 16),
        (unsigned)f2bf(v.z) | ((unsigned)f2bf(v.w) << 16));
  } else {
    int g = bx - 8192;
    int gx = g & 127, gy = g >> 7;
    const float* src; u16* dst; int N, n0;
    if (gx < 32)      { src = Wq;  dst = WqT;  N = 1024; n0 = gx * 32; }
    else if (gx < 96) { src = Wkv; dst = WkvT; N = 2048; n0 = (gx - 32) * 32; }
    else              { src = Wo;  dst = WoT;  N = 1024; n0 = (gx - 96) * 32; }
    int k0 = gy * 32;
    int tx = t & 31, ty = t >> 5;
#pragma unroll
    for (int i = 0; i < 4; ++i)
      tile[ty * 4 + i][tx] = src[(size_t)(k0 + ty * 4 + i) * N + n0 + tx];
    __syncthreads();
#pragma unroll
    for (int i = 0; i < 4; ++i)
      dst[(size_t)(n0 + ty * 4 + i) * 1024 + k0 + tx] = f2bf(tile[tx][ty * 4 + i]);
  }
}

// ---------- fused QKV GEMM: 768 blocks (3/CU), 256 thr, 128x128 tiles ----------
// blocks [0,256): Q-proj -> qb row-major (pre-scaled)
// blocks [256,768): KV-proj -> kf / vf FRAGMENT-MAJOR directly (LDS roundtrip)
//   frag layouts (per b,h,kt 4096-u16 block; chunk (ks,idx); lane=(quad,cl); j=0..7):
//     kf: K[t=kt*64+idx*16+cl][d=ks*32+quad*8+j]
//     vf: V[t=kt*64+ks*32+quad*8+j][d=idx*16+cl]
__global__ __launch_bounds__(256) void qkv_gemm(
    const u16* __restrict__ Xq, const u16* __restrict__ Xc,
    const u16* __restrict__ WqT, const u16* __restrict__ WkvT,
    const float* __restrict__ bq, const float* __restrict__ bkv,
    u16* __restrict__ qb, u16* __restrict__ kf, u16* __restrict__ vf,
    float qscale) {
  __shared__ __align__(16) u16 smem[16896];            // 33 KB: As|Bs, then C-tile
  u16* As = smem;
  u16* Bs = smem + 8192;
  const int tid = threadIdx.x, lane = tid & 63, wave = tid >> 6;
  const int quad = lane >> 4, cl = lane & 15;
  const int wr = (wave >> 1) * 64, wc = (wave & 1) * 64;

  int x = blockIdx.x;
  const u16 *A, *Bt; const float* bias; int N, m0, n0; bool isq;
  if (x < 256) {
    isq = true;  A = Xq; Bt = WqT;  bias = bq;  N = 1024;
    m0 = (x >> 3) * 128; n0 = (x & 7) * 128;
  } else {
    isq = false; x -= 256; A = Xc; Bt = WkvT; bias = bkv; N = 2048;
    m0 = (x >> 4) * 128; n0 = (x & 15) * 128;
  }

  f32x4 acc[4][4] = {};

  for (int k0 = 0; k0 < 1024; k0 += 64) {
#pragma unroll
    for (int it = 0; it < 4; ++it) {
      int chunk = (it * 4 + wave) * 64 + lane;
      int row = chunk >> 3, kc = (chunk & 7) * 8;
      gld_lds16(A + (size_t)(m0 + row) * 1024 + k0 + kc, As + (size_t)(it * 4 + wave) * 512);
      gld_lds16(Bt + (size_t)(n0 + row) * 1024 + k0 + kc, Bs + (size_t)(it * 4 + wave) * 512);
    }
    __syncthreads();
#pragma unroll
    for (int ks = 0; ks < 2; ++ks) {
      short8 af[4], bf[4];
#pragma unroll
      for (int mi = 0; mi < 4; ++mi)
        af[mi] = *(const short8*)(As + (wr + mi * 16 + cl) * 64 + ks * 32 + quad * 8);
#pragma unroll
      for (int ni = 0; ni < 4; ++ni)
        bf[ni] = *(const short8*)(Bs + (wc + ni * 16 + cl) * 64 + ks * 32 + quad * 8);
#pragma unroll
      for (int mi = 0; mi < 4; ++mi)
#pragma unroll
        for (int ni = 0; ni < 4; ++ni)
          acc[mi][ni] = __builtin_amdgcn_mfma_f32_16x16x32_bf16(af[mi], bf[ni], acc[mi][ni], 0, 0, 0);
    }
    __syncthreads();
  }

  if (isq) {
#pragma unroll
    for (int mi = 0; mi < 4; ++mi)
#pragma unroll
      for (int ni = 0; ni < 4; ++ni)
#pragma unroll
        for (int r = 0; r < 4; ++r) {
          int row = m0 + wr + mi * 16 + quad * 4 + r;
          int col = n0 + wc + ni * 16 + cl;
          qb[(size_t)row * 1024 + col] = f2bf((acc[mi][ni][r] + bias[col]) * qscale);
        }
    return;
  }

  const int b = m0 >> 11, kt0 = (m0 & 2047) >> 6;
  const bool kreg = (n0 < 1024);
  if (kreg) {
    // K-tile -> LDS [t][d], stride 132 (scalar b16 stores; b128 frag reads)
#pragma unroll
    for (int mi = 0; mi < 4; ++mi)
#pragma unroll
      for (int ni = 0; ni < 4; ++ni)
#pragma unroll
        for (int r = 0; r < 4; ++r)
          smem[(wr + mi * 16 + quad * 4 + r) * 132 + wc + ni * 16 + cl] =
              f2bf(acc[mi][ni][r] + bias[n0 + wc + ni * 16 + cl]);
    __syncthreads();
#pragma unroll
    for (int i = 0; i < 8; ++i) {
      int c = i * 4 + wave;                       // 32 chunks
      int hs = c >> 4, ts = (c >> 3) & 1, ks = (c >> 2) & 1, idx = c & 3;
      int h = (n0 >> 6) + hs;
      size_t bhkt = ((size_t)((b * 16 + h) * 32 + kt0 + ts)) * 4096;
      short8 v = *(const short8*)(smem + (ts * 64 + idx * 16 + cl) * 132 +
                                  hs * 64 + ks * 32 + quad * 8);
      *(short8*)(kf + bhkt + (size_t)(ks * 4 + idx) * 512 + lane * 8) = v;
    }
  } else {
    // V-tile -> LDS transposed [d][t], stride 132 (packed b64 stores; b128 frag reads)
#pragma unroll
    for (int mi = 0; mi < 4; ++mi)
#pragma unroll
      for (int ni = 0; ni < 4; ++ni) {
        float v0 = acc[mi][ni][0] + bias[n0 + wc + ni * 16 + cl];
        float v1 = acc[mi][ni][1] + bias[n0 + wc + ni * 16 + cl];
        float v2 = acc[mi][ni][2] + bias[n0 + wc + ni * 16 + cl];
        float v3 = acc[mi][ni][3] + bias[n0 + wc + ni * 16 + cl];
        *(uint2*)(smem + (wc + ni * 16 + cl) * 132 + wr + mi * 16 + quad * 4) =
            make_uint2(pack2bf(v0, v1), pack2bf(v2, v3));
      }
    __syncthreads();
#pragma unroll
    for (int i = 0; i < 8; ++i) {
      int c = i * 4 + wave;
      int hs = c >> 4, ts = (c >> 3) & 1, ks = (c >> 2) & 1, idx = c & 3;
      int h = ((n0 - 1024) >> 6) + hs;
      size_t bhkt = ((size_t)((b * 16 + h) * 32 + kt0 + ts)) * 4096;
      short8 v = *(const short8*)(smem + (hs * 64 + idx * 16 + cl) * 132 +
                                  ts * 64 + ks * 32 + quad * 8);
      *(short8*)(vf + bhkt + (size_t)(ks * 4 + idx) * 512 + lane * 8) = v;
    }
  }
}

// ---------- O-proj: 256 blocks, 512 thr = 8 waves (2m x 4n, 64x32/wave) ----------
__global__ __launch_bounds__(512) void o_gemm(
    const u16* __restrict__ A, const u16* __restrict__ Bt,
    const float* __restrict__ bias, float* __restrict__ Cm) {
  __shared__ __align__(16) u16 As[128 * 64];
  __shared__ __align__(16) u16 Bs[128 * 64];
  const int tid = threadIdx.x, lane = tid & 63, wave = tid >> 6;
  const int quad = lane >> 4, cl = lane & 15;
  const int m0 = (blockIdx.x >> 3) * 128, n0 = (blockIdx.x & 7) * 128;
  const int wr = (wave >> 2) * 64, wc = (wave & 3) * 32;

  f32x4 acc[4][2] = {};

  for (int k0 = 0; k0 < 1024; k0 += 64) {
    const int rA = lane >> 3, kc = (lane & 7) * 8;
#pragma unroll
    for (int it = 0; it < 2; ++it) {
      int ch = it * 8 + wave;
      gld_lds16(A + (size_t)(m0 + ch * 8 + rA) * 1024 + k0 + kc, As + ch * 512);
    }
#pragma unroll
    for (int it = 0; it < 2; ++it) {
      int ch = it * 8 + wave;
      gld_lds16(Bt + (size_t)(n0 + ch * 8 + rA) * 1024 + k0 + kc, Bs + ch * 512);
    }
    __syncthreads();
#pragma unroll
    for (int ks = 0; ks < 2; ++ks) {
      short8 af[4], bf[2];
#pragma unroll
      for (int mi = 0; mi < 4; ++mi)
        af[mi] = *(const short8*)(As + (wr + mi * 16 + cl) * 64 + ks * 32 + quad * 8);
#pragma unroll
      for (int ni = 0; ni < 2; ++ni)
        bf[ni] = *(const short8*)(Bs + (wc + ni * 16 + cl) * 64 + ks * 32 + quad * 8);
#pragma unroll
      for (int mi = 0; mi < 4; ++mi)
#pragma unroll
        for (int ni = 0; ni < 2; ++ni)
          acc[mi][ni] = __builtin_amdgcn_mfma_f32_16x16x32_bf16(af[mi], bf[ni], acc[mi][ni], 0, 0, 0);
    }
    __syncthreads();
  }
#pragma unroll
  for (int mi = 0; mi < 4; ++mi)
#pragma unroll
    for (int ni = 0; ni < 2; ++ni)
#pragma unroll
      for (int r = 0; r < 4; ++r) {
        int row = m0 + wr + mi * 16 + quad * 4 + r;
        int col = n0 + wc + ni * 16 + cl;
        Cm[(size_t)row * 1024 + col] = acc[mi][ni][r] + bias[col];
      }
}

// ---------- flash attention: S^T = K.Q^T, 32 Q-rows per wave ----------
// grid (16,16,2), 256 thr = 4 independent waves; wave owns 32 Q rows (2 groups
// of 16). K/V fragment loads are shared across both groups -> VMEM bytes per
// S-element halve vs the 16-row version (the R4/R5 evidence says flash is
// VMEM-path-saturated, occupancy-invariant).
__global__ __launch_bounds__(256) void flash_attn(
    const u16* __restrict__ qb, const u16* __restrict__ kf,
    const u16* __restrict__ vf, u16* __restrict__ outp) {
  __shared__ __align__(16) u16 Pbuf[4][32 * 72];   // per-wave P[m 0..31][t], stride 72
  const int tid = threadIdx.x, lane = tid & 63, wave = tid >> 6;
  const int quad = lane >> 4, cl = lane & 15;
  const int qt = blockIdx.x, h = blockIdx.y, b = blockIdx.z;
  u16* Pw = Pbuf[wave];

  const int qrow0 = b * 2048 + qt * 128 + wave * 32;
  short8 bq[2][2];   // [group][ks]  Q as B-operand: B[n=cl][k=quad*8+j]
#pragma unroll
  for (int g = 0; g < 2; ++g)
#pragma unroll
    for (int ks = 0; ks < 2; ++ks)
      bq[g][ks] = *(const short8*)(qb + (size_t)(qrow0 + g * 16 + cl) * 1024 +
                                   h * 64 + ks * 32 + quad * 8);

  const u16* kfb = kf + (size_t)((b * 16 + h) * 32) * 4096 + lane * 8;
  const u16* vfb = vf + (size_t)((b * 16 + h) * 32) * 4096 + lane * 8;

  f32x4 o_acc[2][4] = {};
  float l_lane[2] = {0.f, 0.f};

  for (int kt = 0; kt < 32; ++kt) {
    const u16* kfk = kfb + (size_t)kt * 4096;
    const u16* vfk = vfb + (size_t)kt * 4096;
    // S^T = K.Q^T : 8 K-frag loads feed both q-groups (16 MFMA)
    f32x4 st[2][4] = {};
#pragma unroll
    for (int ks = 0; ks < 2; ++ks)
#pragma unroll
      for (int ni = 0; ni < 4; ++ni) {
        short8 ak = *(const short8*)(kfk + (ks * 4 + ni) * 512);
        st[0][ni] = __builtin_amdgcn_mfma_f32_16x16x32_bf16(ak, bq[0][ks], st[0][ni], 0, 0, 0);
        st[1][ni] = __builtin_amdgcn_mfma_f32_16x16x32_bf16(ak, bq[1][ks], st[1][ni], 0, 0, 0);
      }
    // p = exp2(s); per-lane row-sum; pack to bf16 -> per-wave LDS
#pragma unroll
    for (int g = 0; g < 2; ++g)
#pragma unroll
      for (int ni = 0; ni < 4; ++ni) {
        float p0 = __builtin_amdgcn_exp2f(st[g][ni][0]);
        float p1 = __builtin_amdgcn_exp2f(st[g][ni][1]);
        float p2 = __builtin_amdgcn_exp2f(st[g][ni][2]);
        float p3 = __builtin_amdgcn_exp2f(st[g][ni][3]);
        l_lane[g] += (p0 + p1) + (p2 + p3);
        *(uint2*)(Pw + (g * 16 + cl) * 72 + ni * 16 + quad * 4) =
            make_uint2(pack2bf(p0, p1), pack2bf(p2, p3));
      }
    // O += P.V : 8 V-frag loads feed both q-groups (16 MFMA)
#pragma unroll
    for (int ks = 0; ks < 2; ++ks) {
      short8 ap0 = *(const short8*)(Pw + (cl) * 72 + ks * 32 + quad * 8);
      short8 ap1 = *(const short8*)(Pw + (16 + cl) * 72 + ks * 32 + quad * 8);
#pragma unroll
      for (int nd = 0; nd < 4; ++nd) {
        short8 bv = *(const short8*)(vfk + (ks * 4 + nd) * 512);
        o_acc[0][nd] = __builtin_amdgcn_mfma_f32_16x16x32_bf16(ap0, bv, o_acc[0][nd], 0, 0, 0);
        o_acc[1][nd] = __builtin_amdgcn_mfma_f32_16x16x32_bf16(ap1, bv, o_acc[1][nd], 0, 0, 0);
      }
    }
  }
#pragma unroll
  for (int g = 0; g < 2; ++g) {
    float l = l_lane[g];
    l += __shfl_xor(l, 16);
    l += __shfl_xor(l, 32);
#pragma unroll
    for (int r = 0; r < 4; ++r) {
      float lr = __shfl(l, (lane & 48) | (quad * 4 + r));
      float inv = 1.f / lr;
      int row = qrow0 + g * 16 + quad * 4 + r;
#pragma unroll
      for (int nd = 0; nd < 4; ++nd)
        outp[(size_t)row * 1024 + h * 64 + nd * 16 + cl] = f2bf(o_acc[g][nd][r] * inv);
    }
  }
}

// ---------- launch ----------
extern "C" void kernel_launch(void* const* d_in, const int* in_sizes, int n_in,
                              void* d_out, int out_size, void* d_ws, size_t ws_size,
                              hipStream_t stream) {
  const float* query   = (const float*)d_in[0];
  const float* context = (const float*)d_in[1];
  const float* Wq  = (const float*)d_in[2];
  const float* bq  = (const float*)d_in[3];
  const float* Wkv = (const float*)d_in[4];
  const float* bkv = (const float*)d_in[5];
  const float* Wo  = (const float*)d_in[6];
  const float* bo  = (const float*)d_in[7];
  float* out = (float*)d_out;

  char* ws = (char*)d_ws;
  size_t off = 0;
  auto alloc = [&](size_t bytes) {
    char* p = ws + off;
    off += (bytes + 255) & ~(size_t)255;
    return p;
  };
  u16* buf0 = (u16*)alloc(4096ull * 1024 * 2);   // Xq -> attn_out
  u16* xcb  = (u16*)alloc(4096ull * 1024 * 2);   // Xc
  u16* WqT  = (u16*)alloc(1024ull * 1024 * 2);
  u16* WkvT = (u16*)alloc(2048ull * 1024 * 2);
  u16* WoT  = (u16*)alloc(1024ull * 1024 * 2);
  u16* qb   = (u16*)alloc(4096ull * 1024 * 2);
  u16* kfr  = (u16*)alloc(4ull * 1024 * 1024 * 2);
  u16* vfr  = (u16*)alloc(4ull * 1024 * 1024 * 2);

  const float QSCALE = 0.125f * 1.44269504f;  // 1/sqrt(64) * log2(e)

  pre_kernel<<<12288, 256, 0, stream>>>(query, context, Wq, Wkv, Wo,
                                        buf0, xcb, WqT, WkvT, WoT);
  qkv_gemm<<<768, 256, 0, stream>>>(buf0, xcb, WqT, WkvT, bq, bkv,
                                    qb, kfr, vfr, QSCALE);
  flash_attn<<<dim3(16, 16, 2), 256, 0, stream>>>(qb, kfr, vfr, buf0);
  o_gemm<<<256, 512, 0, stream>>>(buf0, WoT, bo, out);
}

// Round 7
// 244.106 us; speedup vs baseline: 1.0528x; 1.0528x over previous
//
#include <hip/hip_runtime.h>
#include <math.h>

typedef unsigned short u16;
typedef unsigned int u32;
typedef __attribute__((ext_vector_type(8))) short short8;
typedef __attribute__((ext_vector_type(4))) float f32x4;

// ---------- helpers ----------
__device__ __forceinline__ u16 f2bf(float f) {
  union { float f; unsigned u; } x; x.f = f;
  unsigned r = x.u + 0x7FFFu + ((x.u >> 16) & 1u);   // RNE
  return (u16)(r >> 16);
}

__device__ __forceinline__ u32 asu(float f) {
  union { float f; u32 u; } x; x.f = f; return x.u;
}

// pack two floats -> two bf16 (round-half-up) in one u32: lo=a, hi=b
__device__ __forceinline__ u32 pack2bf(float a, float b) {
  return __builtin_amdgcn_perm(asu(b) + 0x8000u, asu(a) + 0x8000u, 0x07060302u);
}

__device__ __forceinline__ void gld_lds16(const void* g, void* l) {
  __builtin_amdgcn_global_load_lds(
      (const __attribute__((address_space(1))) unsigned int*)g,
      (__attribute__((address_space(3))) unsigned int*)l, 16, 0, 0);
}

// ---------- fused preprocessing: cast Xq/Xc + transpose all weights ----------
__global__ void pre_kernel(const float* __restrict__ q, const float* __restrict__ c,
                           const float* __restrict__ Wq, const float* __restrict__ Wkv,
                           const float* __restrict__ Wo,
                           u16* __restrict__ xq, u16* __restrict__ xc,
                           u16* __restrict__ WqT, u16* __restrict__ WkvT,
                           u16* __restrict__ WoT) {
  __shared__ float tile[32][33];
  int bx = blockIdx.x, t = threadIdx.x;
  if (bx < 8192) {
    int i = bx * 256 + t;
    const float* src = q; u16* dst = xq;
    if (i >= 1048576) { i -= 1048576; src = c; dst = xc; }
    float4 v = ((const float4*)src)[i];
    ((uint2*)dst)[i] = make_uint2(
        (unsigned)f2bf(v.x) | ((unsigned)f2bf(v.y) << 16),
        (unsigned)f2bf(v.z) | ((unsigned)f2bf(v.w) << 16));
  } else {
    int g = bx - 8192;
    int gx = g & 127, gy = g >> 7;
    const float* src; u16* dst; int N, n0;
    if (gx < 32)      { src = Wq;  dst = WqT;  N = 1024; n0 = gx * 32; }
    else if (gx < 96) { src = Wkv; dst = WkvT; N = 2048; n0 = (gx - 32) * 32; }
    else              { src = Wo;  dst = WoT;  N = 1024; n0 = (gx - 96) * 32; }
    int k0 = gy * 32;
    int tx = t & 31, ty = t >> 5;
#pragma unroll
    for (int i = 0; i < 4; ++i)
      tile[ty * 4 + i][tx] = src[(size_t)(k0 + ty * 4 + i) * N + n0 + tx];
    __syncthreads();
#pragma unroll
    for (int i = 0; i < 4; ++i)
      dst[(size_t)(n0 + ty * 4 + i) * 1024 + k0 + tx] = f2bf(tile[tx][ty * 4 + i]);
  }
}

// ---------- fused QKV GEMM: 768 blocks (3/CU), 256 thr, 128x128 tiles ----------
__global__ __launch_bounds__(256) void qkv_gemm(
    const u16* __restrict__ Xq, const u16* __restrict__ Xc,
    const u16* __restrict__ WqT, const u16* __restrict__ WkvT,
    const float* __restrict__ bq, const float* __restrict__ bkv,
    u16* __restrict__ qb, u16* __restrict__ kf, u16* __restrict__ vf,
    float qscale) {
  __shared__ __align__(16) u16 smem[16896];            // 33 KB: As|Bs, then C-tile
  u16* As = smem;
  u16* Bs = smem + 8192;
  const int tid = threadIdx.x, lane = tid & 63, wave = tid >> 6;
  const int quad = lane >> 4, cl = lane & 15;
  const int wr = (wave >> 1) * 64, wc = (wave & 1) * 64;

  int x = blockIdx.x;
  const u16 *A, *Bt; const float* bias; int N, m0, n0; bool isq;
  if (x < 256) {
    isq = true;  A = Xq; Bt = WqT;  bias = bq;  N = 1024;
    m0 = (x >> 3) * 128; n0 = (x & 7) * 128;
  } else {
    isq = false; x -= 256; A = Xc; Bt = WkvT; bias = bkv; N = 2048;
    m0 = (x >> 4) * 128; n0 = (x & 15) * 128;
  }

  f32x4 acc[4][4] = {};

  for (int k0 = 0; k0 < 1024; k0 += 64) {
#pragma unroll
    for (int it = 0; it < 4; ++it) {
      int chunk = (it * 4 + wave) * 64 + lane;
      int row = chunk >> 3, kc = (chunk & 7) * 8;
      gld_lds16(A + (size_t)(m0 + row) * 1024 + k0 + kc, As + (size_t)(it * 4 + wave) * 512);
      gld_lds16(Bt + (size_t)(n0 + row) * 1024 + k0 + kc, Bs + (size_t)(it * 4 + wave) * 512);
    }
    __syncthreads();
#pragma unroll
    for (int ks = 0; ks < 2; ++ks) {
      short8 af[4], bf[4];
#pragma unroll
      for (int mi = 0; mi < 4; ++mi)
        af[mi] = *(const short8*)(As + (wr + mi * 16 + cl) * 64 + ks * 32 + quad * 8);
#pragma unroll
      for (int ni = 0; ni < 4; ++ni)
        bf[ni] = *(const short8*)(Bs + (wc + ni * 16 + cl) * 64 + ks * 32 + quad * 8);
#pragma unroll
      for (int mi = 0; mi < 4; ++mi)
#pragma unroll
        for (int ni = 0; ni < 4; ++ni)
          acc[mi][ni] = __builtin_amdgcn_mfma_f32_16x16x32_bf16(af[mi], bf[ni], acc[mi][ni], 0, 0, 0);
    }
    __syncthreads();
  }

  if (isq) {
#pragma unroll
    for (int mi = 0; mi < 4; ++mi)
#pragma unroll
      for (int ni = 0; ni < 4; ++ni)
#pragma unroll
        for (int r = 0; r < 4; ++r) {
          int row = m0 + wr + mi * 16 + quad * 4 + r;
          int col = n0 + wc + ni * 16 + cl;
          qb[(size_t)row * 1024 + col] = f2bf((acc[mi][ni][r] + bias[col]) * qscale);
        }
    return;
  }

  const int b = m0 >> 11, kt0 = (m0 & 2047) >> 6;
  const bool kreg = (n0 < 1024);
  if (kreg) {
    // K-tile -> LDS [t][d], stride 132 (scalar b16 stores; b128 frag reads)
#pragma unroll
    for (int mi = 0; mi < 4; ++mi)
#pragma unroll
      for (int ni = 0; ni < 4; ++ni)
#pragma unroll
        for (int r = 0; r < 4; ++r)
          smem[(wr + mi * 16 + quad * 4 + r) * 132 + wc + ni * 16 + cl] =
              f2bf(acc[mi][ni][r] + bias[n0 + wc + ni * 16 + cl]);
    __syncthreads();
#pragma unroll
    for (int i = 0; i < 8; ++i) {
      int c = i * 4 + wave;                       // 32 chunks
      int hs = c >> 4, ts = (c >> 3) & 1, ks = (c >> 2) & 1, idx = c & 3;
      int h = (n0 >> 6) + hs;
      size_t bhkt = ((size_t)((b * 16 + h) * 32 + kt0 + ts)) * 4096;
      short8 v = *(const short8*)(smem + (ts * 64 + idx * 16 + cl) * 132 +
                                  hs * 64 + ks * 32 + quad * 8);
      *(short8*)(kf + bhkt + (size_t)(ks * 4 + idx) * 512 + lane * 8) = v;
    }
  } else {
    // V-tile -> LDS transposed [d][t], stride 132 (packed b64 stores; b128 frag reads)
#pragma unroll
    for (int mi = 0; mi < 4; ++mi)
#pragma unroll
      for (int ni = 0; ni < 4; ++ni) {
        float v0 = acc[mi][ni][0] + bias[n0 + wc + ni * 16 + cl];
        float v1 = acc[mi][ni][1] + bias[n0 + wc + ni * 16 + cl];
        float v2 = acc[mi][ni][2] + bias[n0 + wc + ni * 16 + cl];
        float v3 = acc[mi][ni][3] + bias[n0 + wc + ni * 16 + cl];
        *(uint2*)(smem + (wc + ni * 16 + cl) * 132 + wr + mi * 16 + quad * 4) =
            make_uint2(pack2bf(v0, v1), pack2bf(v2, v3));
      }
    __syncthreads();
#pragma unroll
    for (int i = 0; i < 8; ++i) {
      int c = i * 4 + wave;
      int hs = c >> 4, ts = (c >> 3) & 1, ks = (c >> 2) & 1, idx = c & 3;
      int h = ((n0 - 1024) >> 6) + hs;
      size_t bhkt = ((size_t)((b * 16 + h) * 32 + kt0 + ts)) * 4096;
      short8 v = *(const short8*)(smem + (hs * 64 + idx * 16 + cl) * 132 +
                                  ts * 64 + ks * 32 + quad * 8);
      *(short8*)(vf + bhkt + (size_t)(ks * 4 + idx) * 512 + lane * 8) = v;
    }
  }
}

// ---------- O-proj: 256 blocks, 512 thr = 8 waves (2m x 4n, 64x32/wave) ----------
__global__ __launch_bounds__(512) void o_gemm(
    const u16* __restrict__ A, const u16* __restrict__ Bt,
    const float* __restrict__ bias, float* __restrict__ Cm) {
  __shared__ __align__(16) u16 As[128 * 64];
  __shared__ __align__(16) u16 Bs[128 * 64];
  const int tid = threadIdx.x, lane = tid & 63, wave = tid >> 6;
  const int quad = lane >> 4, cl = lane & 15;
  const int m0 = (blockIdx.x >> 3) * 128, n0 = (blockIdx.x & 7) * 128;
  const int wr = (wave >> 2) * 64, wc = (wave & 3) * 32;

  f32x4 acc[4][2] = {};

  for (int k0 = 0; k0 < 1024; k0 += 64) {
    const int rA = lane >> 3, kc = (lane & 7) * 8;
#pragma unroll
    for (int it = 0; it < 2; ++it) {
      int ch = it * 8 + wave;
      gld_lds16(A + (size_t)(m0 + ch * 8 + rA) * 1024 + k0 + kc, As + ch * 512);
    }
#pragma unroll
    for (int it = 0; it < 2; ++it) {
      int ch = it * 8 + wave;
      gld_lds16(Bt + (size_t)(n0 + ch * 8 + rA) * 1024 + k0 + kc, Bs + ch * 512);
    }
    __syncthreads();
#pragma unroll
    for (int ks = 0; ks < 2; ++ks) {
      short8 af[4], bf[2];
#pragma unroll
      for (int mi = 0; mi < 4; ++mi)
        af[mi] = *(const short8*)(As + (wr + mi * 16 + cl) * 64 + ks * 32 + quad * 8);
#pragma unroll
      for (int ni = 0; ni < 2; ++ni)
        bf[ni] = *(const short8*)(Bs + (wc + ni * 16 + cl) * 64 + ks * 32 + quad * 8);
#pragma unroll
      for (int mi = 0; mi < 4; ++mi)
#pragma unroll
        for (int ni = 0; ni < 2; ++ni)
          acc[mi][ni] = __builtin_amdgcn_mfma_f32_16x16x32_bf16(af[mi], bf[ni], acc[mi][ni], 0, 0, 0);
    }
    __syncthreads();
  }
#pragma unroll
  for (int mi = 0; mi < 4; ++mi)
#pragma unroll
    for (int ni = 0; ni < 2; ++ni)
#pragma unroll
      for (int r = 0; r < 4; ++r) {
        int row = m0 + wr + mi * 16 + quad * 4 + r;
        int col = n0 + wc + ni * 16 + cl;
        Cm[(size_t)row * 1024 + col] = acc[mi][ni][r] + bias[col];
      }
}

// ---------- flash attention: S^T = K.Q^T, register-prefetch pipeline ----------
// 1D grid 1024 blocks; id%8 == h%8 so each XCD's L2 caches only its 4 (b,h)
// K/V sets (4 MB). Ping-pong K/V register buffers: loads for kt+1 issue while
// kt computes -> covers L2/L3 load latency (the R4-R6-evidenced limiter).
__global__ __launch_bounds__(256) void flash_attn(
    const u16* __restrict__ qb, const u16* __restrict__ kf,
    const u16* __restrict__ vf, u16* __restrict__ outp) {
  __shared__ __align__(16) u16 Pbuf[4][16 * 72];
  const int tid = threadIdx.x, lane = tid & 63, wave = tid >> 6;
  const int quad = lane >> 4, cl = lane & 15;
  const int id = blockIdx.x;
  const int h = (id & 7) | (((id >> 3) & 1) << 3);
  const int b = (id >> 4) & 1;
  const int qt = id >> 5;
  u16* Pw = Pbuf[wave];

  const int qrow0 = b * 2048 + qt * 64 + wave * 16;
  short8 bq[2];
#pragma unroll
  for (int ks = 0; ks < 2; ++ks)
    bq[ks] = *(const short8*)(qb + (size_t)(qrow0 + cl) * 1024 + h * 64 + ks * 32 + quad * 8);

  const u16* kfb = kf + (size_t)((b * 16 + h) * 32) * 4096 + lane * 8;
  const u16* vfb = vf + (size_t)((b * 16 + h) * 32) * 4096 + lane * 8;

  short8 kbuf[2][8], vbuf[2][8];
#pragma unroll
  for (int i = 0; i < 8; ++i) kbuf[0][i] = *(const short8*)(kfb + i * 512);
#pragma unroll
  for (int i = 0; i < 8; ++i) vbuf[0][i] = *(const short8*)(vfb + i * 512);

  f32x4 o_acc[4] = {};
  float l_lane = 0.f;

#pragma unroll 2
  for (int kt = 0; kt < 32; ++kt) {
    const int cur = kt & 1, nxt = cur ^ 1;
    const int ktn = (kt + 1) & 31;                  // wrap: harmless dead loads on last iter
    const u16* kfn = kfb + (size_t)ktn * 4096;
    const u16* vfn = vfb + (size_t)ktn * 4096;
    // S^T = K.Q^T from current K regs
    f32x4 st[4] = {};
#pragma unroll
    for (int ks = 0; ks < 2; ++ks)
#pragma unroll
      for (int ni = 0; ni < 4; ++ni)
        st[ni] = __builtin_amdgcn_mfma_f32_16x16x32_bf16(kbuf[cur][ks * 4 + ni], bq[ks], st[ni], 0, 0, 0);
    // prefetch next K (latency overlaps exp2/pack/PV below)
#pragma unroll
    for (int i = 0; i < 8; ++i) kbuf[nxt][i] = *(const short8*)(kfn + i * 512);
    // p = exp2(s); per-lane row-sum; pack -> per-wave LDS
#pragma unroll
    for (int ni = 0; ni < 4; ++ni) {
      float p0 = __builtin_amdgcn_exp2f(st[ni][0]);
      float p1 = __builtin_amdgcn_exp2f(st[ni][1]);
      float p2 = __builtin_amdgcn_exp2f(st[ni][2]);
      float p3 = __builtin_amdgcn_exp2f(st[ni][3]);
      l_lane += (p0 + p1) + (p2 + p3);
      *(uint2*)(Pw + cl * 72 + ni * 16 + quad * 4) =
          make_uint2(pack2bf(p0, p1), pack2bf(p2, p3));
    }
    // O += P.V from current V regs
#pragma unroll
    for (int ks = 0; ks < 2; ++ks) {
      short8 ap = *(const short8*)(Pw + cl * 72 + ks * 32 + quad * 8);
#pragma unroll
      for (int nd = 0; nd < 4; ++nd)
        o_acc[nd] = __builtin_amdgcn_mfma_f32_16x16x32_bf16(ap, vbuf[cur][ks * 4 + nd], o_acc[nd], 0, 0, 0);
    }
    // prefetch next V (latency overlaps next iter's S/exp2)
#pragma unroll
    for (int i = 0; i < 8; ++i) vbuf[nxt][i] = *(const short8*)(vfn + i * 512);
  }
  l_lane += __shfl_xor(l_lane, 16);
  l_lane += __shfl_xor(l_lane, 32);
#pragma unroll
  for (int r = 0; r < 4; ++r) {
    float lr = __shfl(l_lane, (lane & 48) | (quad * 4 + r));
    float inv = 1.f / lr;
    int row = qrow0 + quad * 4 + r;
#pragma unroll
    for (int nd = 0; nd < 4; ++nd)
      outp[(size_t)row * 1024 + h * 64 + nd * 16 + cl] = f2bf(o_acc[nd][r] * inv);
  }
}

// ---------- launch ----------
extern "C" void kernel_launch(void* const* d_in, const int* in_sizes, int n_in,
                              void* d_out, int out_size, void* d_ws, size_t ws_size,
                              hipStream_t stream) {
  const float* query   = (const float*)d_in[0];
  const float* context = (const float*)d_in[1];
  const float* Wq  = (const float*)d_in[2];
  const float* bq  = (const float*)d_in[3];
  const float* Wkv = (const float*)d_in[4];
  const float* bkv = (const float*)d_in[5];
  const float* Wo  = (const float*)d_in[6];
  const float* bo  = (const float*)d_in[7];
  float* out = (float*)d_out;

  char* ws = (char*)d_ws;
  size_t off = 0;
  auto alloc = [&](size_t bytes) {
    char* p = ws + off;
    off += (bytes + 255) & ~(size_t)255;
    return p;
  };
  u16* buf0 = (u16*)alloc(4096ull * 1024 * 2);   // Xq -> attn_out
  u16* xcb  = (u16*)alloc(4096ull * 1024 * 2);   // Xc
  u16* WqT  = (u16*)alloc(1024ull * 1024 * 2);
  u16* WkvT = (u16*)alloc(2048ull * 1024 * 2);
  u16* WoT  = (u16*)alloc(1024ull * 1024 * 2);
  u16* qb   = (u16*)alloc(4096ull * 1024 * 2);
  u16* kfr  = (u16*)alloc(4ull * 1024 * 1024 * 2);
  u16* vfr  = (u16*)alloc(4ull * 1024 * 1024 * 2);

  const float QSCALE = 0.125f * 1.44269504f;  // 1/sqrt(64) * log2(e)

  pre_kernel<<<12288, 256, 0, stream>>>(query, context, Wq, Wkv, Wo,
                                        buf0, xcb, WqT, WkvT, WoT);
  qkv_gemm<<<768, 256, 0, stream>>>(buf0, xcb, WqT, WkvT, bq, bkv,
                                    qb, kfr, vfr, QSCALE);
  flash_attn<<<1024, 256, 0, stream>>>(qb, kfr, vfr, buf0);
  o_gemm<<<256, 512, 0, stream>>>(buf0, WoT, bo, out);
}